// Round 1
// baseline (153.653 us; speedup 1.0000x reference)
//
#include <hip/hip_runtime.h>
#include <math.h>

#define NROWS 8192
#define DIM 512
#define INV_T 20.0f
#define LOG_NEG_W 0.69314718055994531f

typedef __attribute__((ext_vector_type(4))) float f32x4;
typedef __attribute__((ext_vector_type(8))) __bf16 bf16x8;
typedef __attribute__((ext_vector_type(4))) __bf16 bf16x4;

__device__ __forceinline__ void gload_lds16(const void* g, void* l) {
    __builtin_amdgcn_global_load_lds(
        (const __attribute__((address_space(1))) unsigned int*)g,
        (__attribute__((address_space(3))) unsigned int*)l, 16, 0, 0);
}

__device__ __forceinline__ float dot4(float4 a, float4 b) {
    return a.x * b.x + a.y * b.y + a.z * b.z + a.w * b.w;
}

__device__ __forceinline__ bf16x4 to_bf4(float4 v, float sc) {
    bf16x4 r;
    r.x = (__bf16)(v.x * sc);
    r.y = (__bf16)(v.y * sc);
    r.z = (__bf16)(v.z * sc);
    r.w = (__bf16)(v.w * sc);
    return r;
}

// One wave per row: normalize a and s to bf16, compute exact fp32 diag,
// column log-weights, and zero the row-sum accumulator.
__global__ __launch_bounds__(256) void norm_kernel(
    const float* __restrict__ A, const float* __restrict__ S,
    const int* __restrict__ labels, __bf16* __restrict__ aB,
    __bf16* __restrict__ sB, float* __restrict__ diag,
    float* __restrict__ logw, float* __restrict__ lsum) {
    const int wave = threadIdx.x >> 6, lane = threadIdx.x & 63;
    const int row = blockIdx.x * 4 + wave;
    const float4* a4 = (const float4*)(A + (size_t)row * DIM);
    const float4* s4 = (const float4*)(S + (size_t)row * DIM);
    float4 a0 = a4[lane], a1 = a4[lane + 64];
    float4 s0 = s4[lane], s1 = s4[lane + 64];
    float saa = dot4(a0, a0) + dot4(a1, a1);
    float sss = dot4(s0, s0) + dot4(s1, s1);
    float sas = dot4(a0, s0) + dot4(a1, s1);
    for (int m = 1; m < 64; m <<= 1) {
        saa += __shfl_xor(saa, m);
        sss += __shfl_xor(sss, m);
        sas += __shfl_xor(sas, m);
    }
    const float ra = rsqrtf(saa), rs = rsqrtf(sss);
    __bf16* arow = aB + (size_t)row * DIM;
    __bf16* srow = sB + (size_t)row * DIM;
    *(bf16x4*)(arow + lane * 4)       = to_bf4(a0, ra);
    *(bf16x4*)(arow + 256 + lane * 4) = to_bf4(a1, ra);
    *(bf16x4*)(srow + lane * 4)       = to_bf4(s0, rs);
    *(bf16x4*)(srow + 256 + lane * 4) = to_bf4(s1, rs);
    if (lane == 0) {
        diag[row] = sas * ra * rs * INV_T;
        logw[row] = (labels[row] == 0) ? LOG_NEG_W : 0.0f;
        lsum[row] = 0.0f;
    }
}

// Fused GEMM + exp + row-sum. 128x128 tile, BK=32, 4 waves (2x2), m97-style
// global_load_lds staging. No max-subtraction needed: logits <= 20.7.
#define BM 128
#define BN 128
#define BK 32

__global__ __launch_bounds__(256, 2) void lse_gemm(
    const __bf16* __restrict__ Abf, const __bf16* __restrict__ Bbf,
    const float* __restrict__ logw, float* __restrict__ lsum) {
    __shared__ __align__(16) __bf16 ldsA[BM * BK];  // 8 KB
    __shared__ __align__(16) __bf16 ldsB[BN * BK];  // 8 KB

    const int nbn = NROWS / BN;  // 64
    const int rt = blockIdx.x / nbn, ct = blockIdx.x % nbn;
    const int row0 = rt * BM, col0 = ct * BN;
    const int tid = threadIdx.x;
    const int wave = tid >> 6, lane = tid & 63;
    const int wm = wave >> 1, wn = wave & 1;

    // staging coords: thread t covers 16B at flat offset t*16 within a 4KB
    // (64-row) chunk: row = t/4, elem = (t%4)*8. LDS dest is wave-uniform.
    const int srow = tid >> 2;
    const int scol = (tid & 3) * 8;

    const __bf16* Ag = Abf + (size_t)row0 * DIM + (size_t)srow * DIM + scol;
    const __bf16* Bg = Bbf + (size_t)col0 * DIM + (size_t)srow * DIM + scol;

    f32x4 acc[4][4] = {};

    const int fr = lane & 15;
    const int ko = (lane >> 4) * 8;

    for (int k0 = 0; k0 < DIM; k0 += BK) {
        __syncthreads();  // previous iter's LDS reads done before overwrite
        gload_lds16(Ag + k0,                 (__bf16*)ldsA + wave * 512);
        gload_lds16(Ag + k0 + 64 * DIM,      (__bf16*)ldsA + 2048 + wave * 512);
        gload_lds16(Bg + k0,                 (__bf16*)ldsB + wave * 512);
        gload_lds16(Bg + k0 + 64 * DIM,      (__bf16*)ldsB + 2048 + wave * 512);
        __syncthreads();  // drains vmcnt: staged data visible

        bf16x8 af[4], bfr[4];
#pragma unroll
        for (int m = 0; m < 4; m++)
            af[m] = *(const bf16x8*)&ldsA[(wm * 64 + m * 16 + fr) * BK + ko];
#pragma unroll
        for (int n = 0; n < 4; n++)
            bfr[n] = *(const bf16x8*)&ldsB[(wn * 64 + n * 16 + fr) * BK + ko];
#pragma unroll
        for (int m = 0; m < 4; m++)
#pragma unroll
            for (int n = 0; n < 4; n++)
                acc[m][n] = __builtin_amdgcn_mfma_f32_16x16x32_bf16(
                    af[m], bfr[n], acc[m][n], 0, 0, 0);
    }

    // Epilogue: logits -> exp -> per-row sums -> atomicAdd.
    // C/D layout: col = lane&15, row = (lane>>4)*4 + j  [m89/m91 verified]
    float lw[4];
    int gc[4];
#pragma unroll
    for (int n = 0; n < 4; n++) {
        gc[n] = col0 + wn * 64 + n * 16 + fr;
        lw[n] = logw[gc[n]];
    }
    const int rgrp = (lane >> 4) * 4;
#pragma unroll
    for (int m = 0; m < 4; m++) {
        const int grbase = row0 + wm * 64 + m * 16 + rgrp;
        float rsum[4] = {0.f, 0.f, 0.f, 0.f};
#pragma unroll
        for (int n = 0; n < 4; n++) {
#pragma unroll
            for (int j = 0; j < 4; j++) {
                const float logit = acc[m][n][j] * INV_T +
                                    ((gc[n] == grbase + j) ? 0.0f : lw[n]);
                rsum[j] += __expf(logit);
            }
        }
#pragma unroll
        for (int j = 0; j < 4; j++) {
            float v = rsum[j];
            v += __shfl_xor(v, 1);
            v += __shfl_xor(v, 2);
            v += __shfl_xor(v, 4);
            v += __shfl_xor(v, 8);
            rsum[j] = v;
        }
        if (fr == 0) {
#pragma unroll
            for (int j = 0; j < 4; j++)
                atomicAdd(&lsum[grbase + j], rsum[j]);
        }
    }
}

// Single block: final scalar reduction.
__global__ __launch_bounds__(256) void finalize_kernel(
    const float* __restrict__ lsum, const float* __restrict__ diag,
    const int* __restrict__ labels, float* __restrict__ out) {
    const int tid = threadIdx.x;
    float sl = 0.f, sd = 0.f, mx = -1e9f;
    int np_ = 0, nn_ = 0;
    for (int i = tid; i < NROWS; i += 256) {
        const float dg = diag[i];
        if (labels[i] == 1) {
            sl += logf(lsum[i]) - dg;
            sd += dg;
            np_++;
        } else {
            nn_++;
            mx = fmaxf(mx, dg);
        }
    }
    for (int m = 1; m < 64; m <<= 1) {
        sl += __shfl_xor(sl, m);
        sd += __shfl_xor(sd, m);
        mx = fmaxf(mx, __shfl_xor(mx, m));
        np_ += __shfl_xor(np_, m);
        nn_ += __shfl_xor(nn_, m);
    }
    __shared__ float rsl[4], rsd[4], rmx[4];
    __shared__ int rnp[4], rnn[4];
    const int wave = tid >> 6, lane = tid & 63;
    if (lane == 0) {
        rsl[wave] = sl; rsd[wave] = sd; rmx[wave] = mx;
        rnp[wave] = np_; rnn[wave] = nn_;
    }
    __syncthreads();
    if (tid == 0) {
        float SL = 0.f, SD = 0.f, MX = -1e9f;
        int NP = 0, NN = 0;
        for (int w = 0; w < 4; w++) {
            SL += rsl[w]; SD += rsd[w]; MX = fmaxf(MX, rmx[w]);
            NP += rnp[w]; NN += rnn[w];
        }
        const float infonce = SL / (float)NP;
        const float meanpos = SD / (float)NP;
        float pen = fmaxf(MX - meanpos + 0.2f, 0.0f);
        if (NN == 0) pen = 0.0f;
        out[0] = infonce + pen;
    }
}

extern "C" void kernel_launch(void* const* d_in, const int* in_sizes, int n_in,
                              void* d_out, int out_size, void* d_ws, size_t ws_size,
                              hipStream_t stream) {
    const float* A = (const float*)d_in[0];
    const float* S = (const float*)d_in[1];
    const int* labels = (const int*)d_in[2];
    float* out = (float*)d_out;

    char* ws = (char*)d_ws;
    __bf16* aB = (__bf16*)ws;                              // 8 MB
    __bf16* sB = (__bf16*)(ws + (size_t)NROWS * DIM * 2);  // 8 MB
    char* p = ws + (size_t)NROWS * DIM * 4;
    float* diag = (float*)p;                // 32 KB
    float* logw = (float*)(p + 32768);      // 32 KB
    float* lsum = (float*)(p + 65536);      // 32 KB

    norm_kernel<<<NROWS / 4, 256, 0, stream>>>(A, S, labels, aB, sB, diag, logw, lsum);
    lse_gemm<<<(NROWS / BM) * (NROWS / BN), 256, 0, stream>>>(aB, sB, logw, lsum);
    finalize_kernel<<<1, 256, 0, stream>>>(lsum, diag, labels, out);
}